// Round 1
// baseline (870.489 us; speedup 1.0000x reference)
//
#include <hip/hip_runtime.h>
#include <stddef.h>

// Problem constants (fixed by reference setup)
#define SROWS   16384
#define ODIM    6144
#define RMAX    64
#define SEGLEN  512
#define TM      32
#define TN      256
#define KC      16

// out[i,n] = scale * sum_{k<keff} x[i, q*keff+k] * W[w, n, k], q = part(n)
// rows with l >= seg_len -> 0
__global__ __launch_bounds__(256, 4) void lora_qkv_b_kernel(
    const float* __restrict__ x,          // (16384, 192)
    const float* __restrict__ w_all,      // (8, 6144, 64)
    const int*   __restrict__ weight_indices, // (32,)
    const int*   __restrict__ lora_ranks,     // (8,)
    const float* __restrict__ scalings,       // (8,)
    const int*   __restrict__ seg_lens,       // (32,)
    float*       __restrict__ out)        // (16384, 6144)
{
    __shared__ float xs[TM][RMAX];        // part-extracted x, zero-padded: 8 KB
    __shared__ float wlds[KC][TN];        // W chunk, k-major: 16 KB

    const int rb = blockIdx.x;            // 0..511  (row block)
    const int cb = blockIdx.y;            // 0..23   (col block)
    const int i0 = rb * TM;
    const int n0 = cb * TN;

    const int seg  = i0 >> 9;             // row block never straddles a segment (32 | 512)
    const int l0   = i0 & (SEGLEN - 1);
    const int w    = weight_indices[seg];
    int keff       = lora_ranks[w];
    if (keff > RMAX) keff = RMAX;
    const float scale = scalings[w];
    const int slen    = seg_lens[seg];
    // part q: TN=256 divides 1024, so a col tile never straddles 4096/5120
    const int q    = (n0 < 4096) ? 0 : ((n0 < 5120) ? 1 : 2);
    const int qoff = q * keff;
    const float* Wb = w_all + ((size_t)w * ODIM + n0) * RMAX;

    const int tid  = threadIdx.x;
    const int wave = tid >> 6;
    const int lane = tid & 63;
    const int rbase  = wave * 8;          // 4 waves x 8 rows = TM
    const int nlocal = lane * 4;          // 64 lanes x 4 cols = TN

    // ---- stage x slice: xs[r][k] = valid ? x[i0+r][qoff+k] : 0 ----
    for (int idx = tid; idx < TM * RMAX; idx += 256) {
        const int r = idx >> 6;
        const int k = idx & (RMAX - 1);
        float v = 0.0f;
        if (k < keff && (l0 + r) < slen) {
            v = x[(size_t)(i0 + r) * 192 + qoff + k];
        }
        xs[r][k] = v;
    }

    float acc[8][4];
    #pragma unroll
    for (int r = 0; r < 8; ++r)
        #pragma unroll
        for (int c = 0; c < 4; ++c) acc[r][c] = 0.0f;

    const int nkc = (keff + KC - 1) / KC; // chunks actually needed (0 if keff==0)

    __syncthreads();

    for (int kc = 0; kc < nkc; ++kc) {
        // ---- stage W chunk: wlds[kk][n] = (k<keff) ? W[n0+n][kc*16+kk] : 0 ----
        {
            const float* wr = Wb + (size_t)tid * RMAX + kc * KC;
            const int krem = keff - kc * KC;
            #pragma unroll
            for (int kk = 0; kk < KC; ++kk) {
                wlds[kk][tid] = (kk < krem) ? wr[kk] : 0.0f;
            }
        }
        __syncthreads();

        const int kb = kc * KC;
        #pragma unroll
        for (int k4 = 0; k4 < KC / 4; ++k4) {
            float4 wv0 = *(const float4*)(&wlds[k4 * 4 + 0][nlocal]);
            float4 wv1 = *(const float4*)(&wlds[k4 * 4 + 1][nlocal]);
            float4 wv2 = *(const float4*)(&wlds[k4 * 4 + 2][nlocal]);
            float4 wv3 = *(const float4*)(&wlds[k4 * 4 + 3][nlocal]);
            #pragma unroll
            for (int r = 0; r < 8; ++r) {
                const float4 xv = *(const float4*)(&xs[rbase + r][kb + k4 * 4]);
                acc[r][0] += xv.x * wv0.x; acc[r][1] += xv.x * wv0.y;
                acc[r][2] += xv.x * wv0.z; acc[r][3] += xv.x * wv0.w;
                acc[r][0] += xv.y * wv1.x; acc[r][1] += xv.y * wv1.y;
                acc[r][2] += xv.y * wv1.z; acc[r][3] += xv.y * wv1.w;
                acc[r][0] += xv.z * wv2.x; acc[r][1] += xv.z * wv2.y;
                acc[r][2] += xv.z * wv2.z; acc[r][3] += xv.z * wv2.w;
                acc[r][0] += xv.w * wv3.x; acc[r][1] += xv.w * wv3.y;
                acc[r][2] += xv.w * wv3.z; acc[r][3] += xv.w * wv3.w;
            }
        }
        __syncthreads();   // reads done before next chunk overwrites wlds
    }

    // ---- epilogue: scale + float4 stores (invalid rows / keff==0 -> zeros) ----
    #pragma unroll
    for (int r = 0; r < 8; ++r) {
        const size_t row = (size_t)(i0 + rbase + r);
        float4 o;
        o.x = acc[r][0] * scale;
        o.y = acc[r][1] * scale;
        o.z = acc[r][2] * scale;
        o.w = acc[r][3] * scale;
        *(float4*)(out + row * ODIM + n0 + nlocal) = o;
    }
}

extern "C" void kernel_launch(void* const* d_in, const int* in_sizes, int n_in,
                              void* d_out, int out_size, void* d_ws, size_t ws_size,
                              hipStream_t stream) {
    // setup_inputs order:
    // 0: x (16384*192 f32), 1: qkv_lora_b (8*6144*64 f32), 2: use_cuda_graph,
    // 3: bs, 4: num_segments, 5: seg_indptr, 6: weight_indices (32 i32),
    // 7: lora_ranks (8 i32), 8: scalings (8 f32), 9: max_len,
    // 10: seg_lens (32 i32), 11: permutation, 12: output_offset, 13: max_qkv_out_dim
    const float* x    = (const float*)d_in[0];
    const float* wb   = (const float*)d_in[1];
    const int*   widx = (const int*)d_in[6];
    const int*   rks  = (const int*)d_in[7];
    const float* scl  = (const float*)d_in[8];
    const int*   sln  = (const int*)d_in[10];
    float* out = (float*)d_out;

    dim3 grid(SROWS / TM, ODIM / TN);
    lora_qkv_b_kernel<<<grid, 256, 0, stream>>>(x, wb, widx, rks, scl, sln, out);
}

// Round 2
// 572.087 us; speedup vs baseline: 1.5216x; 1.5216x over previous
//
#include <hip/hip_runtime.h>
#include <stddef.h>

// Problem constants (fixed by reference setup)
#define SROWS   16384
#define ODIM    6144
#define RMAX    64
#define SEGLEN  512
#define TM      64
#define TN      128

// out[i,n] = scale * sum_{k<keff} x[i, q*keff+k] * W[w, n, k], q = part(n)
// rows with l >= seg_len -> 0
// Single-barrier structure: stage full W tile (contiguous slab, coalesced
// float4) + full x slice once, then barrier-free k-loop.
__global__ __launch_bounds__(256, 3) void lora_qkv_b_kernel(
    const float* __restrict__ x,              // (16384, 192)
    const float* __restrict__ w_all,          // (8, 6144, 64)
    const int*   __restrict__ weight_indices, // (32,)
    const int*   __restrict__ lora_ranks,     // (8,)
    const float* __restrict__ scalings,       // (8,)
    const int*   __restrict__ seg_lens,       // (32,)
    float*       __restrict__ out)            // (16384, 6144)
{
    __shared__ float xs[TM][RMAX];       // 16 KB, zero-padded past keff / invalid rows
    __shared__ float wlds[RMAX][TN + 4]; // 33 KB, k-major; +4 pad keeps 16B align + breaks bank stride

    const int rb = blockIdx.x;           // 0..255 (row block)
    const int cb = blockIdx.y;           // 0..47  (col block)
    const int i0 = rb * TM;
    const int n0 = cb * TN;

    const int seg  = i0 >> 9;            // 64 | 512: row block within one segment
    const int l0   = i0 & (SEGLEN - 1);
    const int w    = weight_indices[seg];
    int keff       = lora_ranks[w];
    if (keff > RMAX) keff = RMAX;
    const float scale = scalings[w];
    const int slen    = seg_lens[seg];
    // part q: TN=128 divides 1024, so a col tile never straddles 4096/5120
    const int q    = (n0 < 4096) ? 0 : ((n0 < 5120) ? 1 : 2);
    const int qoff = q * keff;
    const float* Wb = w_all + ((size_t)w * ODIM + n0) * RMAX; // contiguous TN*64 slab

    const int tid    = threadIdx.x;
    const int rbase  = (tid >> 5) * 8;   // 8 groups x 8 rows = 64 rows
    const int nlocal = (tid & 31) * 4;   // 32 lanes x 4 cols = 128 cols

    // ---- stage W tile: wlds[k][n] = (k<keff) ? W[n0+n][k] : 0 ----
    // Perfectly coalesced: consecutive threads load consecutive float4s.
    for (int idx = tid * 4; idx < TN * RMAX; idx += 256 * 4) {
        const int n  = idx >> 6;
        const int k0 = idx & 63;
        float4 v = make_float4(0.f, 0.f, 0.f, 0.f);
        if (k0 < keff) {
            v = *(const float4*)(Wb + (size_t)n * RMAX + k0);
            if (k0 + 1 >= keff) v.y = 0.f;
            if (k0 + 2 >= keff) v.z = 0.f;
            if (k0 + 3 >= keff) v.w = 0.f;
        }
        wlds[k0 + 0][n] = v.x;
        wlds[k0 + 1][n] = v.y;
        wlds[k0 + 2][n] = v.z;
        wlds[k0 + 3][n] = v.w;
    }

    // ---- stage x slice: xs[r][k] = valid ? x[i0+r][qoff+k] : 0 ----
    // (scalar loads: qoff not 16B-aligned in general; row-contiguous -> coalesced)
    for (int idx = tid; idx < TM * RMAX; idx += 256) {
        const int r = idx >> 6;
        const int k = idx & 63;
        float v = 0.f;
        if (k < keff && (l0 + r) < slen) {
            v = x[(size_t)(i0 + r) * 192 + qoff + k];
        }
        xs[r][k] = v;
    }

    float acc[8][4];
    #pragma unroll
    for (int r = 0; r < 8; ++r)
        #pragma unroll
        for (int c = 0; c < 4; ++c) acc[r][c] = 0.f;

    __syncthreads();   // the only barrier

    const int keff4 = (keff + 3) & ~3;
    for (int k = 0; k < keff4; k += 4) {
        const float4 w0 = *(const float4*)(&wlds[k + 0][nlocal]);
        const float4 w1 = *(const float4*)(&wlds[k + 1][nlocal]);
        const float4 w2 = *(const float4*)(&wlds[k + 2][nlocal]);
        const float4 w3 = *(const float4*)(&wlds[k + 3][nlocal]);
        #pragma unroll
        for (int r = 0; r < 8; ++r) {
            const float4 xv = *(const float4*)(&xs[rbase + r][k]);
            acc[r][0] += xv.x * w0.x; acc[r][1] += xv.x * w0.y;
            acc[r][2] += xv.x * w0.z; acc[r][3] += xv.x * w0.w;
            acc[r][0] += xv.y * w1.x; acc[r][1] += xv.y * w1.y;
            acc[r][2] += xv.y * w1.z; acc[r][3] += xv.y * w1.w;
            acc[r][0] += xv.z * w2.x; acc[r][1] += xv.z * w2.y;
            acc[r][2] += xv.z * w2.z; acc[r][3] += xv.z * w2.w;
            acc[r][0] += xv.w * w3.x; acc[r][1] += xv.w * w3.y;
            acc[r][2] += xv.w * w3.z; acc[r][3] += xv.w * w3.w;
        }
    }

    // ---- epilogue: scale + float4 stores (invalid rows / keff==0 -> zeros) ----
    #pragma unroll
    for (int r = 0; r < 8; ++r) {
        const size_t row = (size_t)(i0 + rbase + r);
        float4 o;
        o.x = acc[r][0] * scale;
        o.y = acc[r][1] * scale;
        o.z = acc[r][2] * scale;
        o.w = acc[r][3] * scale;
        *(float4*)(out + row * ODIM + n0 + nlocal) = o;
    }
}

extern "C" void kernel_launch(void* const* d_in, const int* in_sizes, int n_in,
                              void* d_out, int out_size, void* d_ws, size_t ws_size,
                              hipStream_t stream) {
    // setup_inputs order:
    // 0: x, 1: qkv_lora_b, 2: use_cuda_graph, 3: bs, 4: num_segments,
    // 5: seg_indptr, 6: weight_indices, 7: lora_ranks, 8: scalings,
    // 9: max_len, 10: seg_lens, 11: permutation, 12: output_offset,
    // 13: max_qkv_out_dim
    const float* x    = (const float*)d_in[0];
    const float* wb   = (const float*)d_in[1];
    const int*   widx = (const int*)d_in[6];
    const int*   rks  = (const int*)d_in[7];
    const float* scl  = (const float*)d_in[8];
    const int*   sln  = (const int*)d_in[10];
    float* out = (float*)d_out;

    dim3 grid(SROWS / TM, ODIM / TN);
    lora_qkv_b_kernel<<<grid, 256, 0, stream>>>(x, wb, widx, rks, scl, sln, out);
}